// Round 2
// baseline (228.956 us; speedup 1.0000x reference)
//
#include <hip/hip_runtime.h>
#include <hip/hip_bf16.h>

typedef __attribute__((ext_vector_type(8))) unsigned short u16x8;
typedef __attribute__((ext_vector_type(8))) __bf16        bf16x8;
typedef __attribute__((ext_vector_type(4))) float         f32x4;

static constexpr int B_ = 8192;
static constexpr int I_ = 512;
static constexpr int H_ = 1024;
static constexpr int K_ = 1536;   // I_ + H_

#define AS1 __attribute__((address_space(1)))
#define AS3 __attribute__((address_space(3)))

__device__ __forceinline__ unsigned short f2bf(float f) {
    unsigned int u = __float_as_uint(f);
    u += 0x7FFF + ((u >> 16) & 1);          // round-to-nearest-even
    return (unsigned short)(u >> 16);
}

// fp32 -> bf16 convert, 8 elems/thread, vectorized
__global__ void cvt_bf16_kernel(const float* __restrict__ src,
                                unsigned short* __restrict__ dst, int n8) {
    int i = blockIdx.x * blockDim.x + threadIdx.x;
    if (i >= n8) return;
    const float4* s = (const float4*)src + (size_t)i * 2;
    float4 a = s[0], b = s[1];
    u16x8 o;
    o[0] = f2bf(a.x); o[1] = f2bf(a.y); o[2] = f2bf(a.z); o[3] = f2bf(a.w);
    o[4] = f2bf(b.x); o[5] = f2bf(b.y); o[6] = f2bf(b.z); o[7] = f2bf(b.w);
    *((u16x8*)dst + i) = o;
}

// C[m][n] = sum_k A[m][k] * W[n][k]  (K-major bf16 operands, fp32 accum)
// A split in K: k < I_ from Ax (stride I_), k >= I_ from Ah (stride H_).
// MODE 0 (fused tau+r, grid.x spans N=2048):
//   n < H_ : outf[m*H_+n]        = 1/(softplus(z)+eps)
//   n >= H_: outg[m*H_+(n-H_)]   = bf16(sigmoid(z) * hidden)
// MODE 1 (h): outf = hidden + (tanh(z)-hidden)*invtau
template<int MODE>
__global__ __launch_bounds__(256)
void gemm_ltc(const unsigned short* __restrict__ Ax,
              const unsigned short* __restrict__ Ah,
              const unsigned short* __restrict__ Wt,
              const unsigned short* __restrict__ Wr,
              const float* __restrict__ bt,
              const float* __restrict__ br,
              const float* __restrict__ hidden,
              const float* __restrict__ invtau,
              float* __restrict__ outf,
              unsigned short* __restrict__ outg)
{
    __shared__ __align__(16) unsigned short As[2][128 * 32];
    __shared__ __align__(16) unsigned short Bs[2][128 * 32];

    const int tid = threadIdx.x;
    const int w   = tid >> 6;       // wave 0..3
    const int l   = tid & 63;       // lane
    const int wrw = w >> 1;         // wave row 0..1
    const int wc  = w & 1;          // wave col 0..1
    const int m0  = blockIdx.y * 128;
    const int n0  = blockIdx.x * 128;

    // block-uniform B-side selection
    const unsigned short* Wb = Wt;
    const float* bias = bt;
    bool is_r = false;
    int nb = n0;
    if (MODE == 0 && n0 >= H_) { Wb = Wr; bias = br; is_r = true; nb = n0 - H_; }

    f32x4 acc[4][4];
    #pragma unroll
    for (int i = 0; i < 4; i++)
        #pragma unroll
        for (int j = 0; j < 4; j++)
            acc[i][j] = (f32x4)0.0f;

    // staging lane geometry: lane l covers row lr, LDS 16B-slot (l&3);
    // source slot XOR-swizzled so ds_read can de-conflict: sg = (l&3)^(lr&3)
    const int lr = l >> 2;                  // 0..15 row within 16-row stripe
    const int sg = (l & 3) ^ (lr & 3);      // swizzled global 16B-slot

    auto STAGE = [&](int buf, int kt) {
        const int k0 = kt * 32;
        const unsigned short* Abase;
        int rs, kc;
        if (k0 < I_) { Abase = Ax; rs = I_; kc = k0; }
        else         { Abase = Ah; rs = H_; kc = k0 - I_; }
        #pragma unroll
        for (int it = 0; it < 2; ++it) {
            const int rr = it * 64 + w * 16;
            const unsigned short* g = Abase + (size_t)(m0 + rr + lr) * rs + kc + sg * 8;
            __builtin_amdgcn_global_load_lds((const AS1 void*)g,
                (AS3 void*)(As[buf] + rr * 32), 16, 0, 0);
        }
        #pragma unroll
        for (int it = 0; it < 2; ++it) {
            const int rr = it * 64 + w * 16;
            const unsigned short* g = Wb + (size_t)(nb + rr + lr) * K_ + k0 + sg * 8;
            __builtin_amdgcn_global_load_lds((const AS1 void*)g,
                (AS3 void*)(Bs[buf] + rr * 32), 16, 0, 0);
        }
    };

    // fragment-read lane geometry (swizzled to match STAGE)
    const int fr  = l & 15;
    const int ks  = l >> 4;
    const int sks = ((ks ^ (fr & 3)) * 8);  // swizzled k-slot offset (elements)

    STAGE(0, 0);
    __syncthreads();

    int cur = 0;
    constexpr int NK = K_ / 32;
    for (int kt = 0; kt < NK; ++kt) {
        if (kt + 1 < NK) STAGE(cur ^ 1, kt + 1);   // prefetch overlaps compute

        bf16x8 a[4], b[4];
        #pragma unroll
        for (int mi = 0; mi < 4; mi++)
            a[mi] = *(const bf16x8*)(As[cur] + (wrw * 64 + mi * 16 + fr) * 32 + sks);
        #pragma unroll
        for (int ni = 0; ni < 4; ni++)
            b[ni] = *(const bf16x8*)(Bs[cur] + (wc * 64 + ni * 16 + fr) * 32 + sks);
        #pragma unroll
        for (int mi = 0; mi < 4; mi++)
            #pragma unroll
            for (int ni = 0; ni < 4; ni++)
                acc[mi][ni] = __builtin_amdgcn_mfma_f32_16x16x32_bf16(
                    a[mi], b[ni], acc[mi][ni], 0, 0, 0);

        __syncthreads();   // drains prefetch vmcnt + protects both buffers
        cur ^= 1;
    }

    // epilogue: C/D layout col = lane&15, row = (lane>>4)*4 + j
    const int rsub = (l >> 4) * 4;
    #pragma unroll
    for (int mi = 0; mi < 4; mi++) {
        #pragma unroll
        for (int ni = 0; ni < 4; ni++) {
            const int gnl = nb + wc * 64 + ni * 16 + fr;   // column within H_
            const float bv = bias[gnl];
            #pragma unroll
            for (int j = 0; j < 4; j++) {
                const int gm = m0 + wrw * 64 + mi * 16 + rsub + j;
                const size_t idx = (size_t)gm * H_ + gnl;
                const float z = acc[mi][ni][j] + bv;
                if (MODE == 0) {
                    if (!is_r) {
                        const float sp = (z > 15.f) ? z : log1pf(expf(z));
                        outf[idx] = 1.0f / (sp + 1e-6f);
                    } else {
                        const float r = 1.0f / (1.0f + expf(-z));
                        outg[idx] = f2bf(r * hidden[idx]);
                    }
                } else {
                    const float h = hidden[idx];
                    outf[idx] = h + (tanhf(z) - h) * invtau[idx];
                }
            }
        }
    }
}

extern "C" void kernel_launch(void* const* d_in, const int* in_sizes, int n_in,
                              void* d_out, int out_size, void* d_ws, size_t ws_size,
                              hipStream_t stream) {
    (void)in_sizes; (void)n_in; (void)out_size; (void)ws_size;

    const float* x     = (const float*)d_in[0];
    const float* hid   = (const float*)d_in[1];
    const float* W_tau = (const float*)d_in[2];
    const float* b_tau = (const float*)d_in[3];
    const float* W_r   = (const float*)d_in[4];
    const float* b_r   = (const float*)d_in[5];
    const float* W_h   = (const float*)d_in[6];
    const float* b_h   = (const float*)d_in[7];

    // workspace layout (~85 MB)
    unsigned short* xb    = (unsigned short*)d_ws;                 // B_*I_
    unsigned short* hb    = xb    + (size_t)B_ * I_;               // B_*H_
    unsigned short* gated = hb    + (size_t)B_ * H_;               // B_*H_
    unsigned short* wtb   = gated + (size_t)B_ * H_;               // H_*K_
    unsigned short* wrb   = wtb   + (size_t)H_ * K_;               // H_*K_
    unsigned short* whb   = wrb   + (size_t)H_ * K_;               // H_*K_
    float*          itau  = (float*)(whb + (size_t)H_ * K_);       // B_*H_ f32

    const int th = 256;
    const int nxi = B_ * I_ / 8, nh = B_ * H_ / 8, nw = H_ * K_ / 8;
    cvt_bf16_kernel<<<(nxi + th - 1) / th, th, 0, stream>>>(x,     xb,  nxi);
    cvt_bf16_kernel<<<(nh  + th - 1) / th, th, 0, stream>>>(hid,   hb,  nh);
    cvt_bf16_kernel<<<(nw  + th - 1) / th, th, 0, stream>>>(W_tau, wtb, nw);
    cvt_bf16_kernel<<<(nw  + th - 1) / th, th, 0, stream>>>(W_r,   wrb, nw);
    cvt_bf16_kernel<<<(nw  + th - 1) / th, th, 0, stream>>>(W_h,   whb, nw);

    dim3 g0(2048 / 128, B_ / 128);   // fused tau+r: 16 x 64
    gemm_ltc<0><<<g0, 256, 0, stream>>>(xb, hb, wtb, wrb, b_tau, b_r, hid,
                                        nullptr, itau, gated);
    dim3 g1(H_ / 128, B_ / 128);     // h: 8 x 64
    gemm_ltc<1><<<g1, 256, 0, stream>>>(xb, gated, whb, nullptr, b_h, nullptr,
                                        hid, itau, (float*)d_out, nullptr);
}

// Round 4
// 187.046 us; speedup vs baseline: 1.2241x; 1.2241x over previous
//
#include <hip/hip_runtime.h>
#include <hip/hip_bf16.h>

typedef __attribute__((ext_vector_type(8))) unsigned short u16x8;
typedef __attribute__((ext_vector_type(8))) __bf16        bf16x8;
typedef __attribute__((ext_vector_type(4))) float         f32x4;

static constexpr int B_ = 8192;
static constexpr int I_ = 512;
static constexpr int H_ = 1024;
static constexpr int K_ = 1536;   // I_ + H_
static constexpr int NT    = K_ / 64;   // 24 K-tiles of BK=64
static constexpr int NITER = NT / 2;    // 12 iterations (2 tiles each)

#define AS1 __attribute__((address_space(1)))
#define AS3 __attribute__((address_space(3)))

__device__ __forceinline__ unsigned short f2bf(float f) {
    unsigned int u = __float_as_uint(f);
    u += 0x7FFF + ((u >> 16) & 1);          // RNE
    return (unsigned short)(u >> 16);
}

__device__ __forceinline__ void memfence() { asm volatile("" ::: "memory"); }
__device__ __forceinline__ void barrier_() {
    memfence(); __builtin_amdgcn_s_barrier(); memfence();
}

// ---- fp32 -> bf16 packers -------------------------------------------------
__global__ void cvt_pack(const float* __restrict__ src,
                         unsigned short* __restrict__ d1,
                         unsigned short* __restrict__ d2,
                         int colShift, int dstOff, int n8) {
    int i = blockIdx.x * blockDim.x + threadIdx.x;
    if (i >= n8) return;
    int row = i >> colShift, c8 = i & ((1 << colShift) - 1);
    const float4* s = (const float4*)src + (size_t)i * 2;
    float4 a = s[0], b = s[1];
    u16x8 o;
    o[0] = f2bf(a.x); o[1] = f2bf(a.y); o[2] = f2bf(a.z); o[3] = f2bf(a.w);
    o[4] = f2bf(b.x); o[5] = f2bf(b.y); o[6] = f2bf(b.z); o[7] = f2bf(b.w);
    size_t di = (size_t)row * K_ + dstOff + c8 * 8;
    *(u16x8*)(d1 + di) = o;
    if (d2) *(u16x8*)(d2 + di) = o;
}

__global__ void cvt_plain(const float* __restrict__ src,
                          unsigned short* __restrict__ dst, int n8) {
    int i = blockIdx.x * blockDim.x + threadIdx.x;
    if (i >= n8) return;
    const float4* s = (const float4*)src + (size_t)i * 2;
    float4 a = s[0], b = s[1];
    u16x8 o;
    o[0] = f2bf(a.x); o[1] = f2bf(a.y); o[2] = f2bf(a.z); o[3] = f2bf(a.w);
    o[4] = f2bf(b.x); o[5] = f2bf(b.y); o[6] = f2bf(b.z); o[7] = f2bf(b.w);
    *((u16x8*)dst + i) = o;
}

// ---- 8-phase 256-tile GEMM (m201-style, plain HIP) ------------------------
// C[m][n] = sum_k A[m][k]*W[n][k], bf16 in, fp32 accum. BM=256, BK=64.
// Half h of A = global rows [h*128, h*128+128); half h of B = [h*BN/2, ...).
// Reads are half-aligned: wave wm reads A rows half*128 + wm*(MH*16)+[0..MH*16);
// wave wn reads B rows half*(BN/2) + wn*32 + [0..32). Every stage of half X
// is issued strictly after the last read of half X (race-free, re-derived).
// MODE 0 (fused tau+r, BN=256): n<H_: itau_out=bf16(1/(softplus+eps));
//                               n>=H_: gate_out[m*K_+512+n'] = bf16(sig*hid)
// MODE 1 (h, BN=128): outF = hid + (tanh(z)-hid)*itau
template<int MODE, int BN, int WN, int LB>
__global__ __launch_bounds__(512, 1)
void gemm8(const unsigned short* __restrict__ A,
           const unsigned short* __restrict__ W,
           const float* __restrict__ b0,
           const float* __restrict__ b1,
           const float* __restrict__ hidden,
           const unsigned short* __restrict__ itau_in,
           float* __restrict__ outF,
           unsigned short* __restrict__ itau_out,
           unsigned short* __restrict__ gate_out)
{
    constexpr int WM = 8 / WN;          // wave grid WM x WN
    constexpr int MI = 256 / (WM * 16); // m-frags per wave (8 or 4)
    constexpr int MH = MI / 2;          // m-frags per half
    constexpr int BUF_B = BN * 128;     // bytes per B K-tile buffer
    extern __shared__ __align__(16) char lds[];
    // LDS: A: [0, 65536) = 2 bufs x 32768 ; B: [65536, 65536+2*BUF_B)

    const int t = threadIdx.x;
    const int w = t >> 6, l = t & 63;
    const int m0 = blockIdx.y * 256;
    const int n0 = blockIdx.x * BN;

    // ---- staging geometry: linear LDS dest, source slot pre-XOR-swizzled
    const int srow  = t >> 3;                       // 0..63
    const int sslot = ((t & 7) ^ (srow & 7)) * 8;   // swizzled 16B slot (elems)
    const unsigned short* srcA = A + (size_t)(m0 + srow) * K_ + sslot;
    const unsigned short* srcB = W + (size_t)(n0 + srow) * K_ + sslot;
    char* dstA = lds + w * 1024;
    char* dstB = lds + 65536 + w * 1024;

    auto stageA = [&](int tt, int h) {   // A half h = rows [h*128, h*128+128)
        const unsigned short* s = srcA + (size_t)(h * 128) * K_ + tt * 64;
        char* d = dstA + (tt & 1) * 32768 + h * 16384;
        #pragma unroll
        for (int j = 0; j < 2; ++j)
            __builtin_amdgcn_global_load_lds(
                (const AS1 void*)(s + (size_t)j * 64 * K_),
                (AS3 void*)(d + j * 8192), 16, 0, 0);
    };
    auto stageB = [&](int tt, int h) {   // B half h = rows [h*BN/2, +BN/2)
        const unsigned short* s = srcB + (size_t)(h * (LB * 64)) * K_ + tt * 64;
        char* d = dstB + (tt & 1) * BUF_B + h * (BUF_B / 2);
        #pragma unroll
        for (int j = 0; j < LB; ++j)
            __builtin_amdgcn_global_load_lds(
                (const AS1 void*)(s + (size_t)j * 64 * K_),
                (AS3 void*)(d + j * 8192), 16, 0, 0);
    };

    // ---- fragment read geometry (same XOR on the read side), half-aligned
    const int fr = l & 15, kq = l >> 4;
    const int wm = w / WN, wn = w % WN;
    const int fx = (kq ^ (fr & 7)) << 4;
    const char* rdA0 = lds + (wm * (MH * 16) + fr) * 128 + fx;
    const char* rdA1 = lds + (wm * (MH * 16) + fr) * 128 + (fx ^ 64);
    const char* rdB0 = lds + 65536 + (wn * 32 + fr) * 128 + fx;
    const char* rdB1 = lds + 65536 + (wn * 32 + fr) * 128 + (fx ^ 64);

    bf16x8 af[MH][2], bfr[2][2];
    f32x4 acc[MI][4];
    #pragma unroll
    for (int i = 0; i < MI; ++i)
        #pragma unroll
        for (int jn = 0; jn < 4; ++jn) acc[i][jn] = (f32x4)0.0f;

    auto readA = [&](int half, int par) {   // rows half*128 + wm*(MH*16)+mi*16+fr
        #pragma unroll
        for (int mi = 0; mi < MH; ++mi) {
            af[mi][0] = *(const bf16x8*)(rdA0 + par * 32768 + half * 16384 + mi * 2048);
            af[mi][1] = *(const bf16x8*)(rdA1 + par * 32768 + half * 16384 + mi * 2048);
        }
    };
    auto readB = [&](int half, int par) {   // rows half*(BN/2) + wn*32+ni*16+fr
        #pragma unroll
        for (int ni = 0; ni < 2; ++ni) {
            bfr[ni][0] = *(const bf16x8*)(rdB0 + par * BUF_B + half * (BUF_B / 2) + ni * 2048);
            bfr[ni][1] = *(const bf16x8*)(rdB1 + par * BUF_B + half * (BUF_B / 2) + ni * 2048);
        }
    };
    auto quad = [&](int ah, int bh) {
        __builtin_amdgcn_s_setprio(1);
        #pragma unroll
        for (int mi = 0; mi < MH; ++mi)
            #pragma unroll
            for (int ni = 0; ni < 2; ++ni)
                #pragma unroll
                for (int ks = 0; ks < 2; ++ks)
                    acc[ah * MH + mi][bh * 2 + ni] =
                        __builtin_amdgcn_mfma_f32_16x16x32_bf16(
                            af[mi][ks], bfr[ni][ks],
                            acc[ah * MH + mi][bh * 2 + ni], 0, 0, 0);
        __builtin_amdgcn_s_setprio(0);
    };
    auto vwait = [&]() {   // steady-state: 2 stageA + 1 stageB groups in flight
        if constexpr (LB == 2) asm volatile("s_waitcnt vmcnt(6)" ::: "memory");
        else                   asm volatile("s_waitcnt vmcnt(5)" ::: "memory");
        __builtin_amdgcn_sched_barrier(0);
    };

    // ---- prologue: tile0 (4 groups, drained) + tile1 partial (3 groups)
    stageA(0, 0); stageB(0, 1); stageA(0, 1); stageB(0, 0);
    stageA(1, 0); stageB(1, 1); stageA(1, 1);
    vwait(); barrier_();

    for (int j = 0; j < NITER; ++j) {
        const int tE = (2 * j + 2 < NT) ? 2 * j + 2 : 0;   // clamped redundant stage
        const int tO = (2 * j + 3 < NT) ? 2 * j + 3 : 0;
        // P1: tile 2j (buf0): A-lo x B-lo          (A-lo last read here)
        readA(0, 0); readB(0, 0); stageB(2 * j + 1, 0);
        barrier_(); quad(0, 0); barrier_();
        // P2: A-lo x B-hi                          (B-hi last read here)
        readB(1, 0); stageA(tE, 0);
        barrier_(); quad(0, 1); barrier_();
        // P3: A-hi x B-hi                          (A-hi last read here)
        readA(1, 0); stageB(tE, 1);
        barrier_(); quad(1, 1); barrier_();
        // P4: A-hi x B-lo                          (B-lo last read here)
        readB(0, 0); stageA(tE, 1);
        barrier_(); quad(1, 0); vwait(); barrier_();
        // P5: tile 2j+1 (buf1): A-lo x B-lo
        readA(0, 1); readB(0, 1); stageB(tE, 0);
        barrier_(); quad(0, 0); barrier_();
        // P6: A-lo x B-hi
        readB(1, 1); stageA(tO, 0);
        barrier_(); quad(0, 1); barrier_();
        // P7: A-hi x B-hi
        readA(1, 1); stageB(tO, 1);
        barrier_(); quad(1, 1); barrier_();
        // P8: A-hi x B-lo
        readB(0, 1); stageA(tO, 1);
        barrier_(); quad(1, 0); vwait(); barrier_();
    }
    asm volatile("s_waitcnt vmcnt(0)" ::: "memory");  // drain clamped stages

    // ---- epilogue: C/D layout col = lane&15, row = (lane>>4)*4 + jj
    const int rs4 = kq * 4;
    const bool isR = (MODE == 0) && (n0 >= H_);
    const float* bias = (MODE == 0) ? (isR ? b1 : b0) : b0;
    const int nB0 = n0 - (isR ? H_ : 0) + wn * 32;
    const int mB0 = m0 + wm * (MH * 16);
    #pragma unroll
    for (int ah = 0; ah < 2; ++ah) {
        #pragma unroll
        for (int mi = 0; mi < MH; ++mi) {
            #pragma unroll
            for (int bh = 0; bh < 2; ++bh) {
                #pragma unroll
                for (int ni = 0; ni < 2; ++ni) {
                    const int n = nB0 + bh * (BN / 2) + ni * 16 + fr;
                    const float bv = bias[n];
                    const int ai = ah * MH + mi, jc = bh * 2 + ni;
                    #pragma unroll
                    for (int jj = 0; jj < 4; ++jj) {
                        const int m = mB0 + ah * 128 + mi * 16 + rs4 + jj;
                        const size_t ix = (size_t)m * H_ + n;
                        const float z = acc[ai][jc][jj] + bv;
                        if (MODE == 0) {
                            if (!isR) {
                                const float sp = (z > 15.f) ? z : log1pf(expf(z));
                                itau_out[ix] = f2bf(1.0f / (sp + 1e-6f));
                            } else {
                                const float r = 1.0f / (1.0f + expf(-z));
                                gate_out[(size_t)m * K_ + 512 + n] = f2bf(r * hidden[ix]);
                            }
                        } else {
                            const float h = hidden[ix];
                            const float it = __uint_as_float(((unsigned)itau_in[ix]) << 16);
                            outF[ix] = h + (tanhf(z) - h) * it;
                        }
                    }
                }
            }
        }
    }
}

extern "C" void kernel_launch(void* const* d_in, const int* in_sizes, int n_in,
                              void* d_out, int out_size, void* d_ws, size_t ws_size,
                              hipStream_t stream) {
    (void)in_sizes; (void)n_in; (void)out_size; (void)ws_size;

    const float* x     = (const float*)d_in[0];
    const float* hid   = (const float*)d_in[1];
    const float* W_tau = (const float*)d_in[2];
    const float* b_tau = (const float*)d_in[3];
    const float* W_r   = (const float*)d_in[4];
    const float* b_r   = (const float*)d_in[5];
    const float* W_h   = (const float*)d_in[6];
    const float* b_h   = (const float*)d_in[7];

    // workspace (~76.5 MB)
    unsigned short* cmb1 = (unsigned short*)d_ws;          // [8192][1536] = [x|hidden]
    unsigned short* cmb2 = cmb1 + (size_t)B_ * K_;         // [8192][1536] = [x|gated]
    unsigned short* wtr  = cmb2 + (size_t)B_ * K_;         // [2048][1536] = [W_tau;W_r]
    unsigned short* whb  = wtr  + (size_t)2048 * K_;       // [1024][1536]
    unsigned short* itau = whb  + (size_t)1024 * K_;       // [8192][1024] bf16

    hipFuncSetAttribute(reinterpret_cast<const void*>(&gemm8<0, 256, 4, 2>),
                        hipFuncAttributeMaxDynamicSharedMemorySize, 131072);
    hipFuncSetAttribute(reinterpret_cast<const void*>(&gemm8<1, 128, 2, 1>),
                        hipFuncAttributeMaxDynamicSharedMemorySize, 98304);

    const int th = 256;
    cvt_pack<<<(B_ * I_ / 8 + th - 1) / th, th, 0, stream>>>(x, cmb1, cmb2, 6, 0, B_ * I_ / 8);
    cvt_pack<<<(B_ * H_ / 8 + th - 1) / th, th, 0, stream>>>(hid, cmb1, nullptr, 7, 512, B_ * H_ / 8);
    const int nw = H_ * K_ / 8;
    cvt_plain<<<(nw + th - 1) / th, th, 0, stream>>>(W_tau, wtr, nw);
    cvt_plain<<<(nw + th - 1) / th, th, 0, stream>>>(W_r, wtr + (size_t)H_ * K_, nw);
    cvt_plain<<<(nw + th - 1) / th, th, 0, stream>>>(W_h, whb, nw);

    dim3 g0(2048 / 256, B_ / 256);   // 8 x 32 = 256 blocks
    gemm8<0, 256, 4, 2><<<g0, 512, 131072, stream>>>(
        cmb1, wtr, b_tau, b_r, hid, nullptr, nullptr, itau, cmb2);
    dim3 g1(1024 / 128, B_ / 256);   // 8 x 32 = 256 blocks
    gemm8<1, 128, 2, 1><<<g1, 512, 98304, stream>>>(
        cmb2, whb, b_h, nullptr, hid, itau, (float*)d_out, nullptr, nullptr);
}

// Round 6
// 172.388 us; speedup vs baseline: 1.3281x; 1.0850x over previous
//
#include <hip/hip_runtime.h>
#include <hip/hip_bf16.h>

typedef __attribute__((ext_vector_type(8))) unsigned short u16x8;
typedef __attribute__((ext_vector_type(8))) __bf16        bf16x8;
typedef __attribute__((ext_vector_type(4))) float         f32x4;

static constexpr int B_ = 8192;
static constexpr int I_ = 512;
static constexpr int H_ = 1024;
static constexpr int K_ = 1536;   // I_ + H_
static constexpr int NT    = K_ / 64;   // 24 K-tiles of BK=64
static constexpr int NITER = NT / 2;    // 12 iterations (2 tiles each)

#define AS1 __attribute__((address_space(1)))
#define AS3 __attribute__((address_space(3)))

__device__ __forceinline__ unsigned short f2bf(float f) {
    unsigned int u = __float_as_uint(f);
    u += 0x7FFF + ((u >> 16) & 1);          // RNE
    return (unsigned short)(u >> 16);
}

__device__ __forceinline__ void memfence() { asm volatile("" ::: "memory"); }
__device__ __forceinline__ void barrier_() {
    memfence(); __builtin_amdgcn_s_barrier(); memfence();
}
__device__ __forceinline__ void vwait6() {
    asm volatile("s_waitcnt vmcnt(6)" ::: "memory");
    __builtin_amdgcn_sched_barrier(0);
}
__device__ __forceinline__ void vwait5() {
    asm volatile("s_waitcnt vmcnt(5)" ::: "memory");
    __builtin_amdgcn_sched_barrier(0);
}

__device__ __forceinline__ u16x8 cvt8(const float4* s) {
    float4 a = s[0], b = s[1];
    u16x8 o;
    o[0] = f2bf(a.x); o[1] = f2bf(a.y); o[2] = f2bf(a.z); o[3] = f2bf(a.w);
    o[4] = f2bf(b.x); o[5] = f2bf(b.y); o[6] = f2bf(b.z); o[7] = f2bf(b.w);
    return o;
}

// ---- pack [x | hidden] -> cmb1, x -> cmb2 (x part) ------------------------
__global__ void pack_xh(const float* __restrict__ x, const float* __restrict__ hid,
                        unsigned short* __restrict__ cmb1,
                        unsigned short* __restrict__ cmb2) {
    constexpr int NX8 = B_ * I_ / 8;   // 524288
    constexpr int NH8 = B_ * H_ / 8;   // 1048576
    int i = blockIdx.x * blockDim.x + threadIdx.x;
    if (i < NX8) {
        int row = i >> 6, c8 = i & 63;
        u16x8 o = cvt8((const float4*)x + (size_t)i * 2);
        size_t di = (size_t)row * K_ + c8 * 8;
        *(u16x8*)(cmb1 + di) = o;
        *(u16x8*)(cmb2 + di) = o;
    } else if (i < NX8 + NH8) {
        int j = i - NX8;
        int row = j >> 7, c8 = j & 127;
        u16x8 o = cvt8((const float4*)hid + (size_t)j * 2);
        *(u16x8*)(cmb1 + (size_t)row * K_ + 512 + c8 * 8) = o;
    }
}

// ---- convert 3 weight matrices ------------------------------------------
__global__ void cvt_w3(const float* __restrict__ wt, const float* __restrict__ wr,
                       const float* __restrict__ wh,
                       unsigned short* __restrict__ wtr,
                       unsigned short* __restrict__ whb) {
    constexpr int NW8 = H_ * K_ / 8;   // 196608
    int i = blockIdx.x * blockDim.x + threadIdx.x;
    const float* src; unsigned short* dst; int k;
    if (i < NW8)           { src = wt; dst = wtr;                     k = i; }
    else if (i < 2 * NW8)  { src = wr; dst = wtr + (size_t)H_ * K_;   k = i - NW8; }
    else if (i < 3 * NW8)  { src = wh; dst = whb;                     k = i - 2 * NW8; }
    else return;
    u16x8 o = cvt8((const float4*)src + (size_t)k * 2);
    *(u16x8*)(dst + (size_t)k * 8) = o;
}

// ===========================================================================
// gemm_fused: BM=256, BN=256 over N=2048 ([W_tau;W_r]), 8-phase (R4-proven)
// + XCD-aware swizzle (XCD c <- m-panels [4c,4c+4): A-panels L2-resident).
//   n<H_:  itau_out = bf16(1/(softplus(z)+eps))
//   n>=H_: gate_out[m*K_+512+n'] = bf16(sigmoid(z)*hidden)
// ===========================================================================
__global__ __launch_bounds__(512, 1)
void gemm_fused(const unsigned short* __restrict__ A,
                const unsigned short* __restrict__ W,
                const float* __restrict__ b0,
                const float* __restrict__ b1,
                const float* __restrict__ hidden,
                unsigned short* __restrict__ itau_out,
                unsigned short* __restrict__ gate_out)
{
    extern __shared__ __align__(16) char lds[];
    // A: [0,65536) 2 bufs x 32768 ; B: [65536,131072) 2 bufs x 32768

    const int t = threadIdx.x;
    const int w = t >> 6, l = t & 63;
    // XCD swizzle: wg%8 = XCD (round-robin dispatch); give each XCD a
    // contiguous chunk of 32 blocks = 4 m-panels x 8 n-blocks.
    const int wg  = blockIdx.y * 8 + blockIdx.x;
    const int swz = (wg & 7) * 32 + (wg >> 3);
    const int m0  = (swz >> 3) * 256;
    const int n0  = (swz & 7) * 256;

    const int srow  = t >> 3;
    const int sslot = ((t & 7) ^ (srow & 7)) * 8;
    const unsigned short* srcA = A + (size_t)(m0 + srow) * K_ + sslot;
    const unsigned short* srcB = W + (size_t)(n0 + srow) * K_ + sslot;
    char* dstA = lds + w * 1024;
    char* dstB = lds + 65536 + w * 1024;

    auto stageA = [&](int tt, int h) {
        const unsigned short* s = srcA + (size_t)(h * 128) * K_ + tt * 64;
        char* d = dstA + (tt & 1) * 32768 + h * 16384;
        #pragma unroll
        for (int j = 0; j < 2; ++j)
            __builtin_amdgcn_global_load_lds(
                (const AS1 void*)(s + (size_t)j * 64 * K_),
                (AS3 void*)(d + j * 8192), 16, 0, 0);
    };
    auto stageB = [&](int tt, int h) {
        const unsigned short* s = srcB + (size_t)(h * 128) * K_ + tt * 64;
        char* d = dstB + (tt & 1) * 32768 + h * 16384;
        #pragma unroll
        for (int j = 0; j < 2; ++j)
            __builtin_amdgcn_global_load_lds(
                (const AS1 void*)(s + (size_t)j * 64 * K_),
                (AS3 void*)(d + j * 8192), 16, 0, 0);
    };

    const int fr = l & 15, kq = l >> 4;
    const int wm = w >> 2, wn = w & 3;                 // waves 2 x 4
    const int fx = (kq ^ (fr & 7)) << 4;
    const char* rdA0 = lds + (wm * 64 + fr) * 128 + fx;
    const char* rdA1 = lds + (wm * 64 + fr) * 128 + (fx ^ 64);
    const char* rdB0 = lds + 65536 + (wn * 32 + fr) * 128 + fx;
    const char* rdB1 = lds + 65536 + (wn * 32 + fr) * 128 + (fx ^ 64);

    bf16x8 af[4][2], bfr[2][2];
    f32x4 acc[8][4];
    #pragma unroll
    for (int i = 0; i < 8; ++i)
        #pragma unroll
        for (int jn = 0; jn < 4; ++jn) acc[i][jn] = (f32x4)0.0f;

    auto readA = [&](int half, int par) {
        #pragma unroll
        for (int mi = 0; mi < 4; ++mi) {
            af[mi][0] = *(const bf16x8*)(rdA0 + par * 32768 + half * 16384 + mi * 2048);
            af[mi][1] = *(const bf16x8*)(rdA1 + par * 32768 + half * 16384 + mi * 2048);
        }
    };
    auto readB = [&](int half, int par) {
        #pragma unroll
        for (int ni = 0; ni < 2; ++ni) {
            bfr[ni][0] = *(const bf16x8*)(rdB0 + par * 32768 + half * 16384 + ni * 2048);
            bfr[ni][1] = *(const bf16x8*)(rdB1 + par * 32768 + half * 16384 + ni * 2048);
        }
    };
    auto quad = [&](int ah, int bh) {
        __builtin_amdgcn_s_setprio(1);
        #pragma unroll
        for (int mi = 0; mi < 4; ++mi)
            #pragma unroll
            for (int ni = 0; ni < 2; ++ni)
                #pragma unroll
                for (int ks = 0; ks < 2; ++ks)
                    acc[ah * 4 + mi][bh * 2 + ni] =
                        __builtin_amdgcn_mfma_f32_16x16x32_bf16(
                            af[mi][ks], bfr[ni][ks],
                            acc[ah * 4 + mi][bh * 2 + ni], 0, 0, 0);
        __builtin_amdgcn_s_setprio(0);
    };

    // prologue: tile0 full + tile1 partial (A-lo, B-hi, A-hi)
    stageA(0, 0); stageB(0, 1); stageA(0, 1); stageB(0, 0);
    stageA(1, 0); stageB(1, 1); stageA(1, 1);
    vwait6(); barrier_();

    for (int j = 0; j < NITER; ++j) {
        const int tE = (2 * j + 2 < NT) ? 2 * j + 2 : 0;
        const int tO = (2 * j + 3 < NT) ? 2 * j + 3 : 0;
        readA(0, 0); readB(0, 0); stageB(2 * j + 1, 0);
        barrier_(); quad(0, 0); barrier_();
        readB(1, 0); stageA(tE, 0);
        barrier_(); quad(0, 1); barrier_();
        readA(1, 0); stageB(tE, 1);
        barrier_(); quad(1, 1); barrier_();
        readB(0, 0); stageA(tE, 1);
        barrier_(); quad(1, 0); vwait6(); barrier_();
        readA(0, 1); readB(0, 1); stageB(tE, 0);
        barrier_(); quad(0, 0); barrier_();
        readB(1, 1); stageA(tO, 0);
        barrier_(); quad(0, 1); barrier_();
        readA(1, 1); stageB(tO, 1);
        barrier_(); quad(1, 1); barrier_();
        readB(0, 1); stageA(tO, 1);
        barrier_(); quad(1, 0); vwait6(); barrier_();
    }
    asm volatile("s_waitcnt vmcnt(0)" ::: "memory");

    const int rs4 = kq * 4;
    const bool isR = (n0 >= H_);
    const float* bias = isR ? b1 : b0;
    const int nB0 = n0 - (isR ? H_ : 0) + wn * 32;
    const int mB0 = m0 + wm * 64;
    #pragma unroll
    for (int ah = 0; ah < 2; ++ah)
        #pragma unroll
        for (int mi = 0; mi < 4; ++mi)
            #pragma unroll
            for (int bh = 0; bh < 2; ++bh)
                #pragma unroll
                for (int ni = 0; ni < 2; ++ni) {
                    const int n = nB0 + bh * 128 + ni * 16 + fr;
                    const float bv = bias[n];
                    #pragma unroll
                    for (int jj = 0; jj < 4; ++jj) {
                        const int m = mB0 + ah * 128 + mi * 16 + rs4 + jj;
                        const size_t ix = (size_t)m * H_ + n;
                        const float z = acc[ah * 4 + mi][bh * 2 + ni][jj] + bv;
                        if (!isR) {
                            const float sp = (z > 15.f) ? z : log1pf(expf(z));
                            itau_out[ix] = f2bf(1.0f / (sp + 1e-6f));
                        } else {
                            const float r = 1.0f / (1.0f + expf(-z));
                            gate_out[(size_t)m * K_ + 512 + n] = f2bf(r * hidden[ix]);
                        }
                    }
                }
}

// ===========================================================================
// gemm_h: EXACT R4-proven 8-phase structure (gemm8<1,128,2,1>): BM=256,
// BN=128, waves 4x2, LB=1, vmcnt(5). + XCD swizzle.
//   out = hidden + (tanh(z)-hidden)*itau
// ===========================================================================
__global__ __launch_bounds__(512, 1)
void gemm_h(const unsigned short* __restrict__ A,
            const unsigned short* __restrict__ W,
            const float* __restrict__ bias,
            const float* __restrict__ hidden,
            const unsigned short* __restrict__ itau_in,
            float* __restrict__ outF)
{
    extern __shared__ __align__(16) char lds[];
    // A: [0,65536) 2 bufs x 32768 ; B: [65536,98304) 2 bufs x 16384

    const int t = threadIdx.x;
    const int w = t >> 6, l = t & 63;
    const int wg  = blockIdx.y * 8 + blockIdx.x;
    const int swz = (wg & 7) * 32 + (wg >> 3);
    const int m0  = (swz >> 3) * 256;
    const int n0  = (swz & 7) * 128;

    const int srow  = t >> 3;
    const int sslot = ((t & 7) ^ (srow & 7)) * 8;
    const unsigned short* srcA = A + (size_t)(m0 + srow) * K_ + sslot;
    const unsigned short* srcB = W + (size_t)(n0 + srow) * K_ + sslot;
    char* dstA = lds + w * 1024;
    char* dstB = lds + 65536 + w * 1024;

    auto stageA = [&](int tt, int h) {   // A half h = rows [h*128, h*128+128)
        const unsigned short* s = srcA + (size_t)(h * 128) * K_ + tt * 64;
        char* d = dstA + (tt & 1) * 32768 + h * 16384;
        #pragma unroll
        for (int j = 0; j < 2; ++j)
            __builtin_amdgcn_global_load_lds(
                (const AS1 void*)(s + (size_t)j * 64 * K_),
                (AS3 void*)(d + j * 8192), 16, 0, 0);
    };
    auto stageB = [&](int tt, int h) {   // B half h = rows [h*64, h*64+64), 1 load
        const unsigned short* s = srcB + (size_t)(h * 64) * K_ + tt * 64;
        char* d = dstB + (tt & 1) * 16384 + h * 8192;
        __builtin_amdgcn_global_load_lds((const AS1 void*)s, (AS3 void*)d, 16, 0, 0);
    };

    const int fr = l & 15, kq = l >> 4;
    const int wm = w >> 1, wn = w & 1;                 // waves 4 x 2
    const int fx = (kq ^ (fr & 7)) << 4;
    const char* rdA0 = lds + (wm * 32 + fr) * 128 + fx;
    const char* rdA1 = lds + (wm * 32 + fr) * 128 + (fx ^ 64);
    const char* rdB0 = lds + 65536 + (wn * 32 + fr) * 128 + fx;
    const char* rdB1 = lds + 65536 + (wn * 32 + fr) * 128 + (fx ^ 64);

    bf16x8 af[2][2], bfr[2][2];
    f32x4 acc[4][4];
    #pragma unroll
    for (int i = 0; i < 4; ++i)
        #pragma unroll
        for (int jn = 0; jn < 4; ++jn) acc[i][jn] = (f32x4)0.0f;

    auto readA = [&](int half, int par) {
        #pragma unroll
        for (int mi = 0; mi < 2; ++mi) {
            af[mi][0] = *(const bf16x8*)(rdA0 + par * 32768 + half * 16384 + mi * 2048);
            af[mi][1] = *(const bf16x8*)(rdA1 + par * 32768 + half * 16384 + mi * 2048);
        }
    };
    auto readB = [&](int half, int par) {
        #pragma unroll
        for (int ni = 0; ni < 2; ++ni) {
            bfr[ni][0] = *(const bf16x8*)(rdB0 + par * 16384 + half * 8192 + ni * 2048);
            bfr[ni][1] = *(const bf16x8*)(rdB1 + par * 16384 + half * 8192 + ni * 2048);
        }
    };
    auto quad = [&](int ah, int bh) {
        __builtin_amdgcn_s_setprio(1);
        #pragma unroll
        for (int mi = 0; mi < 2; ++mi)
            #pragma unroll
            for (int ni = 0; ni < 2; ++ni)
                #pragma unroll
                for (int ks = 0; ks < 2; ++ks)
                    acc[ah * 2 + mi][bh * 2 + ni] =
                        __builtin_amdgcn_mfma_f32_16x16x32_bf16(
                            af[mi][ks], bfr[ni][ks],
                            acc[ah * 2 + mi][bh * 2 + ni], 0, 0, 0);
        __builtin_amdgcn_s_setprio(0);
    };

    // prologue: tile0 full (A4+B2=6 loads) + tile1 partial (A-lo, B-hi, A-hi)
    stageA(0, 0); stageB(0, 1); stageA(0, 1); stageB(0, 0);
    stageA(1, 0); stageB(1, 1); stageA(1, 1);
    vwait5(); barrier_();

    for (int j = 0; j < NITER; ++j) {
        const int tE = (2 * j + 2 < NT) ? 2 * j + 2 : 0;
        const int tO = (2 * j + 3 < NT) ? 2 * j + 3 : 0;
        readA(0, 0); readB(0, 0); stageB(2 * j + 1, 0);
        barrier_(); quad(0, 0); barrier_();
        readB(1, 0); stageA(tE, 0);
        barrier_(); quad(0, 1); barrier_();
        readA(1, 0); stageB(tE, 1);
        barrier_(); quad(1, 1); barrier_();
        readB(0, 0); stageA(tE, 1);
        barrier_(); quad(1, 0); vwait5(); barrier_();
        readA(0, 1); readB(0, 1); stageB(tE, 0);
        barrier_(); quad(0, 0); barrier_();
        readB(1, 1); stageA(tO, 0);
        barrier_(); quad(0, 1); barrier_();
        readA(1, 1); stageB(tO, 1);
        barrier_(); quad(1, 1); barrier_();
        readB(0, 1); stageA(tO, 1);
        barrier_(); quad(1, 0); vwait5(); barrier_();
    }
    asm volatile("s_waitcnt vmcnt(0)" ::: "memory");

    const int rs4 = kq * 4;
    const int nB0 = n0 + wn * 32;
    const int mB0 = m0 + wm * 32;
    #pragma unroll
    for (int ah = 0; ah < 2; ++ah)
        #pragma unroll
        for (int mi = 0; mi < 2; ++mi)
            #pragma unroll
            for (int bh = 0; bh < 2; ++bh)
                #pragma unroll
                for (int ni = 0; ni < 2; ++ni) {
                    const int n = nB0 + bh * 64 + ni * 16 + fr;
                    const float bv = bias[n];
                    #pragma unroll
                    for (int jj = 0; jj < 4; ++jj) {
                        const int m = mB0 + ah * 128 + mi * 16 + rs4 + jj;
                        const size_t ix = (size_t)m * H_ + n;
                        const float z = acc[ah * 2 + mi][bh * 2 + ni][jj] + bv;
                        const float h = hidden[ix];
                        const float it = __uint_as_float(((unsigned)itau_in[ix]) << 16);
                        outF[ix] = h + (tanhf(z) - h) * it;
                    }
                }
}

extern "C" void kernel_launch(void* const* d_in, const int* in_sizes, int n_in,
                              void* d_out, int out_size, void* d_ws, size_t ws_size,
                              hipStream_t stream) {
    (void)in_sizes; (void)n_in; (void)out_size; (void)ws_size;

    const float* x     = (const float*)d_in[0];
    const float* hid   = (const float*)d_in[1];
    const float* W_tau = (const float*)d_in[2];
    const float* b_tau = (const float*)d_in[3];
    const float* W_r   = (const float*)d_in[4];
    const float* b_r   = (const float*)d_in[5];
    const float* W_h   = (const float*)d_in[6];
    const float* b_h   = (const float*)d_in[7];

    // workspace (~76.5 MB)
    unsigned short* cmb1 = (unsigned short*)d_ws;          // [8192][1536] = [x|hidden]
    unsigned short* cmb2 = cmb1 + (size_t)B_ * K_;         // [8192][1536] = [x|gated]
    unsigned short* wtr  = cmb2 + (size_t)B_ * K_;         // [2048][1536] = [W_tau;W_r]
    unsigned short* whb  = wtr  + (size_t)2048 * K_;       // [1024][1536]
    unsigned short* itau = whb  + (size_t)1024 * K_;       // [8192][1024] bf16

    hipFuncSetAttribute(reinterpret_cast<const void*>(&gemm_fused),
                        hipFuncAttributeMaxDynamicSharedMemorySize, 131072);
    hipFuncSetAttribute(reinterpret_cast<const void*>(&gemm_h),
                        hipFuncAttributeMaxDynamicSharedMemorySize, 98304);

    const int th = 256;
    constexpr int NPACK = B_ * I_ / 8 + B_ * H_ / 8;   // 1572864
    pack_xh<<<NPACK / th, th, 0, stream>>>(x, hid, cmb1, cmb2);
    constexpr int NW3 = 3 * H_ * K_ / 8;               // 589824
    cvt_w3<<<NW3 / th, th, 0, stream>>>(W_tau, W_r, W_h, wtr, whb);

    dim3 g0(8, 32);
    gemm_fused<<<g0, 512, 131072, stream>>>(cmb1, wtr, b_tau, b_r, hid, itau, cmb2);
    dim3 g1(8, 32);
    gemm_h<<<g1, 512, 98304, stream>>>(cmb2, whb, b_h, hid, itau, (float*)d_out);
}

// Round 7
// 151.507 us; speedup vs baseline: 1.5112x; 1.1378x over previous
//
#include <hip/hip_runtime.h>
#include <hip/hip_bf16.h>

typedef __attribute__((ext_vector_type(8))) unsigned short u16x8;
typedef __attribute__((ext_vector_type(8))) __bf16        bf16x8;
typedef __attribute__((ext_vector_type(4))) float         f32x4;

static constexpr int B_ = 8192;
static constexpr int I_ = 512;
static constexpr int H_ = 1024;
static constexpr int K_ = 1536;   // I_ + H_
static constexpr int NT    = K_ / 64;   // 24 K-tiles of BK=64
static constexpr int NITER = NT / 2;    // 12 iterations (2 tiles each)

#define AS1 __attribute__((address_space(1)))
#define AS3 __attribute__((address_space(3)))

__device__ __forceinline__ unsigned short f2bf(float f) {
    unsigned int u = __float_as_uint(f);
    u += 0x7FFF + ((u >> 16) & 1);          // RNE
    return (unsigned short)(u >> 16);
}

__device__ __forceinline__ void memfence() { asm volatile("" ::: "memory"); }
__device__ __forceinline__ void barrier_() {
    memfence(); __builtin_amdgcn_s_barrier(); memfence();
}
__device__ __forceinline__ void vwait5() {
    asm volatile("s_waitcnt vmcnt(5)" ::: "memory");
    __builtin_amdgcn_sched_barrier(0);
}

__device__ __forceinline__ u16x8 cvt8(const float4* s) {
    float4 a = s[0], b = s[1];
    u16x8 o;
    o[0] = f2bf(a.x); o[1] = f2bf(a.y); o[2] = f2bf(a.z); o[3] = f2bf(a.w);
    o[4] = f2bf(b.x); o[5] = f2bf(b.y); o[6] = f2bf(b.z); o[7] = f2bf(b.w);
    return o;
}

// ---- pack [x | hidden] -> cmb1, x -> cmb2 (x part) ------------------------
__global__ void pack_xh(const float* __restrict__ x, const float* __restrict__ hid,
                        unsigned short* __restrict__ cmb1,
                        unsigned short* __restrict__ cmb2) {
    constexpr int NX8 = B_ * I_ / 8;   // 524288
    constexpr int NH8 = B_ * H_ / 8;   // 1048576
    int i = blockIdx.x * blockDim.x + threadIdx.x;
    if (i < NX8) {
        int row = i >> 6, c8 = i & 63;
        u16x8 o = cvt8((const float4*)x + (size_t)i * 2);
        size_t di = (size_t)row * K_ + c8 * 8;
        *(u16x8*)(cmb1 + di) = o;
        *(u16x8*)(cmb2 + di) = o;
    } else if (i < NX8 + NH8) {
        int j = i - NX8;
        int row = j >> 7, c8 = j & 127;
        u16x8 o = cvt8((const float4*)hid + (size_t)j * 2);
        *(u16x8*)(cmb1 + (size_t)row * K_ + 512 + c8 * 8) = o;
    }
}

// ---- convert 3 weight matrices ------------------------------------------
__global__ void cvt_w3(const float* __restrict__ wt, const float* __restrict__ wr,
                       const float* __restrict__ wh,
                       unsigned short* __restrict__ wtb,
                       unsigned short* __restrict__ wrb,
                       unsigned short* __restrict__ whb) {
    constexpr int NW8 = H_ * K_ / 8;   // 196608
    int i = blockIdx.x * blockDim.x + threadIdx.x;
    const float* src; unsigned short* dst; int k;
    if (i < NW8)           { src = wt; dst = wtb; k = i; }
    else if (i < 2 * NW8)  { src = wr; dst = wrb; k = i - NW8; }
    else if (i < 3 * NW8)  { src = wh; dst = whb; k = i - 2 * NW8; }
    else return;
    u16x8 o = cvt8((const float4*)src + (size_t)k * 2);
    *(u16x8*)(dst + (size_t)k * 8) = o;
}

// ===========================================================================
// gemm3<MODE>: the R6-proven gemm_h structure (BM=256, BN=128, waves 4x2,
// LB=1, vwait5, 8 phases) with ONE barrier per phase (post-quad only; safety:
// each wave's ds_reads complete before its MFMAs, which precede its barrier
// arrival; stages into that region are issued only after the barrier).
//   MODE 0: itau_out = bf16(1/(softplus(z)+eps))
//   MODE 1: gate_out[m*K_+512+n] = bf16(sigmoid(z)*hidden)
//   MODE 2: outF = hidden + (tanh(z)-hidden)*itau
// ===========================================================================
template<int MODE>
__global__ __launch_bounds__(512, 1)
void gemm3(const unsigned short* __restrict__ A,
           const unsigned short* __restrict__ W,
           const float* __restrict__ bias,
           const float* __restrict__ hidden,
           const unsigned short* __restrict__ itau_in,
           float* __restrict__ outF,
           unsigned short* __restrict__ itau_out,
           unsigned short* __restrict__ gate_out)
{
    extern __shared__ __align__(16) char lds[];
    // A: [0,65536) 2 bufs x 32768 ; B: [65536,98304) 2 bufs x 16384

    const int t = threadIdx.x;
    const int w = t >> 6, l = t & 63;
    const int wg  = blockIdx.y * 8 + blockIdx.x;
    const int swz = (wg & 7) * 32 + (wg >> 3);   // XCD c <- 4 m-panels x 8 n
    const int m0  = (swz >> 3) * 256;
    const int n0  = (swz & 7) * 128;

    const int srow  = t >> 3;
    const int sslot = ((t & 7) ^ (srow & 7)) * 8;
    const unsigned short* srcA = A + (size_t)(m0 + srow) * K_ + sslot;
    const unsigned short* srcB = W + (size_t)(n0 + srow) * K_ + sslot;
    char* dstA = lds + w * 1024;
    char* dstB = lds + 65536 + w * 1024;

    auto stageA = [&](int tt, int h) {   // A half h = rows [h*128, h*128+128)
        const unsigned short* s = srcA + (size_t)(h * 128) * K_ + tt * 64;
        char* d = dstA + (tt & 1) * 32768 + h * 16384;
        #pragma unroll
        for (int j = 0; j < 2; ++j)
            __builtin_amdgcn_global_load_lds(
                (const AS1 void*)(s + (size_t)j * 64 * K_),
                (AS3 void*)(d + j * 8192), 16, 0, 0);
    };
    auto stageB = [&](int tt, int h) {   // B half h = rows [h*64, h*64+64)
        const unsigned short* s = srcB + (size_t)(h * 64) * K_ + tt * 64;
        char* d = dstB + (tt & 1) * 16384 + h * 8192;
        __builtin_amdgcn_global_load_lds((const AS1 void*)s, (AS3 void*)d, 16, 0, 0);
    };

    const int fr = l & 15, kq = l >> 4;
    const int wm = w >> 1, wn = w & 1;                 // waves 4 x 2
    const int fx = (kq ^ (fr & 7)) << 4;
    const char* rdA0 = lds + (wm * 32 + fr) * 128 + fx;
    const char* rdA1 = lds + (wm * 32 + fr) * 128 + (fx ^ 64);
    const char* rdB0 = lds + 65536 + (wn * 32 + fr) * 128 + fx;
    const char* rdB1 = lds + 65536 + (wn * 32 + fr) * 128 + (fx ^ 64);

    bf16x8 af[2][2], bfr[2][2];
    f32x4 acc[4][4];
    #pragma unroll
    for (int i = 0; i < 4; ++i)
        #pragma unroll
        for (int jn = 0; jn < 4; ++jn) acc[i][jn] = (f32x4)0.0f;

    auto readA = [&](int half, int par) {
        #pragma unroll
        for (int mi = 0; mi < 2; ++mi) {
            af[mi][0] = *(const bf16x8*)(rdA0 + par * 32768 + half * 16384 + mi * 2048);
            af[mi][1] = *(const bf16x8*)(rdA1 + par * 32768 + half * 16384 + mi * 2048);
        }
    };
    auto readB = [&](int half, int par) {
        #pragma unroll
        for (int ni = 0; ni < 2; ++ni) {
            bfr[ni][0] = *(const bf16x8*)(rdB0 + par * 16384 + half * 8192 + ni * 2048);
            bfr[ni][1] = *(const bf16x8*)(rdB1 + par * 16384 + half * 8192 + ni * 2048);
        }
    };
    auto quad = [&](int ah, int bh) {
        __builtin_amdgcn_s_setprio(1);
        #pragma unroll
        for (int mi = 0; mi < 2; ++mi)
            #pragma unroll
            for (int ni = 0; ni < 2; ++ni)
                #pragma unroll
                for (int ks = 0; ks < 2; ++ks)
                    acc[ah * 2 + mi][bh * 2 + ni] =
                        __builtin_amdgcn_mfma_f32_16x16x32_bf16(
                            af[mi][ks], bfr[ni][ks],
                            acc[ah * 2 + mi][bh * 2 + ni], 0, 0, 0);
        __builtin_amdgcn_s_setprio(0);
    };

    // prologue: tile0 full (6 loads) + tile1 partial (A-lo, B-hi, A-hi)
    stageA(0, 0); stageB(0, 1); stageA(0, 1); stageB(0, 0);
    stageA(1, 0); stageB(1, 1); stageA(1, 1);
    vwait5(); barrier_();

    for (int j = 0; j < NITER; ++j) {
        const int tE = (2 * j + 2 < NT) ? 2 * j + 2 : 0;
        const int tO = (2 * j + 3 < NT) ? 2 * j + 3 : 0;
        // one barrier per phase: reads+stage+quad, then barrier
        readA(0, 0); readB(0, 0); stageB(2 * j + 1, 0); quad(0, 0); barrier_();
        readB(1, 0); stageA(tE, 0);                      quad(0, 1); barrier_();
        readA(1, 0); stageB(tE, 1);                      quad(1, 1); barrier_();
        readB(0, 0); stageA(tE, 1);                      quad(1, 0); vwait5(); barrier_();
        readA(0, 1); readB(0, 1); stageB(tE, 0);         quad(0, 0); barrier_();
        readB(1, 1); stageA(tO, 0);                      quad(0, 1); barrier_();
        readA(1, 1); stageB(tO, 1);                      quad(1, 1); barrier_();
        readB(0, 1); stageA(tO, 1);                      quad(1, 0); vwait5(); barrier_();
    }
    asm volatile("s_waitcnt vmcnt(0)" ::: "memory");

    const int rs4 = kq * 4;
    const int nB0 = n0 + wn * 32;
    const int mB0 = m0 + wm * 32;
    #pragma unroll
    for (int ah = 0; ah < 2; ++ah)
        #pragma unroll
        for (int mi = 0; mi < 2; ++mi)
            #pragma unroll
            for (int bh = 0; bh < 2; ++bh)
                #pragma unroll
                for (int ni = 0; ni < 2; ++ni) {
                    const int n = nB0 + bh * 64 + ni * 16 + fr;
                    const float bv = bias[n];
                    #pragma unroll
                    for (int jj = 0; jj < 4; ++jj) {
                        const int m = mB0 + ah * 128 + mi * 16 + rs4 + jj;
                        const size_t ix = (size_t)m * H_ + n;
                        const float z = acc[ah * 2 + mi][bh * 2 + ni][jj] + bv;
                        if (MODE == 0) {
                            const float sp = (z > 15.f) ? z : log1pf(expf(z));
                            itau_out[ix] = f2bf(1.0f / (sp + 1e-6f));
                        } else if (MODE == 1) {
                            const float r = 1.0f / (1.0f + expf(-z));
                            gate_out[(size_t)m * K_ + 512 + n] = f2bf(r * hidden[ix]);
                        } else {
                            const float h = hidden[ix];
                            const float it = __uint_as_float(((unsigned)itau_in[ix]) << 16);
                            outF[ix] = h + (tanhf(z) - h) * it;
                        }
                    }
                }
}

extern "C" void kernel_launch(void* const* d_in, const int* in_sizes, int n_in,
                              void* d_out, int out_size, void* d_ws, size_t ws_size,
                              hipStream_t stream) {
    (void)in_sizes; (void)n_in; (void)out_size; (void)ws_size;

    const float* x     = (const float*)d_in[0];
    const float* hid   = (const float*)d_in[1];
    const float* W_tau = (const float*)d_in[2];
    const float* b_tau = (const float*)d_in[3];
    const float* W_r   = (const float*)d_in[4];
    const float* b_r   = (const float*)d_in[5];
    const float* W_h   = (const float*)d_in[6];
    const float* b_h   = (const float*)d_in[7];

    // workspace (~76.5 MB)
    unsigned short* cmb1 = (unsigned short*)d_ws;          // [8192][1536] = [x|hidden]
    unsigned short* cmb2 = cmb1 + (size_t)B_ * K_;         // [8192][1536] = [x|gated]
    unsigned short* wtb  = cmb2 + (size_t)B_ * K_;         // [1024][1536]
    unsigned short* wrb  = wtb  + (size_t)H_ * K_;         // [1024][1536]
    unsigned short* whb  = wrb  + (size_t)H_ * K_;         // [1024][1536]
    unsigned short* itau = whb  + (size_t)H_ * K_;         // [8192][1024] bf16

    hipFuncSetAttribute(reinterpret_cast<const void*>(&gemm3<0>),
                        hipFuncAttributeMaxDynamicSharedMemorySize, 98304);
    hipFuncSetAttribute(reinterpret_cast<const void*>(&gemm3<1>),
                        hipFuncAttributeMaxDynamicSharedMemorySize, 98304);
    hipFuncSetAttribute(reinterpret_cast<const void*>(&gemm3<2>),
                        hipFuncAttributeMaxDynamicSharedMemorySize, 98304);

    const int th = 256;
    constexpr int NPACK = B_ * I_ / 8 + B_ * H_ / 8;   // 1572864
    pack_xh<<<NPACK / th, th, 0, stream>>>(x, hid, cmb1, cmb2);
    constexpr int NW3 = 3 * H_ * K_ / 8;               // 589824
    cvt_w3<<<NW3 / th, th, 0, stream>>>(W_tau, W_r, W_h, wtb, wrb, whb);

    dim3 g(8, 32);   // 256 blocks, 1/CU
    gemm3<0><<<g, 512, 98304, stream>>>(cmb1, wtb, b_tau, nullptr, nullptr,
                                        nullptr, itau, nullptr);
    gemm3<1><<<g, 512, 98304, stream>>>(cmb1, wrb, b_r, hid, nullptr,
                                        nullptr, nullptr, cmb2);
    gemm3<2><<<g, 512, 98304, stream>>>(cmb2, whb, b_h, hid, itau,
                                        (float*)d_out, nullptr, nullptr);
}

// Round 8
// 125.033 us; speedup vs baseline: 1.8312x; 1.2117x over previous
//
#include <hip/hip_runtime.h>
#include <hip/hip_bf16.h>

typedef __attribute__((ext_vector_type(8))) unsigned short u16x8;
typedef __attribute__((ext_vector_type(8))) __bf16        bf16x8;
typedef __attribute__((ext_vector_type(4))) float         f32x4;

static constexpr int B_ = 8192;
static constexpr int I_ = 512;
static constexpr int H_ = 1024;
static constexpr int K_ = 1536;   // I_ + H_
static constexpr int NT    = K_ / 64;   // 24 K-tiles of BK=64
static constexpr int NITER = NT / 2;    // 12 iterations (2 tiles each)

#define AS1 __attribute__((address_space(1)))
#define AS3 __attribute__((address_space(3)))

__device__ __forceinline__ unsigned short f2bf(float f) {
    unsigned int u = __float_as_uint(f);
    u += 0x7FFF + ((u >> 16) & 1);          // RNE
    return (unsigned short)(u >> 16);
}

__device__ __forceinline__ void memfence() { asm volatile("" ::: "memory"); }
__device__ __forceinline__ void barrier_() {
    memfence(); __builtin_amdgcn_s_barrier(); memfence();
}
__device__ __forceinline__ void vwait4() {
    asm volatile("s_waitcnt vmcnt(4)" ::: "memory");
    __builtin_amdgcn_sched_barrier(0);
}

__device__ __forceinline__ u16x8 cvt8(const float4* s) {
    float4 a = s[0], b = s[1];
    u16x8 o;
    o[0] = f2bf(a.x); o[1] = f2bf(a.y); o[2] = f2bf(a.z); o[3] = f2bf(a.w);
    o[4] = f2bf(b.x); o[5] = f2bf(b.y); o[6] = f2bf(b.z); o[7] = f2bf(b.w);
    return o;
}

// ---- pack [x | hidden] -> cmb1 (bf16) -------------------------------------
__global__ void pack_xh(const float* __restrict__ x, const float* __restrict__ hid,
                        unsigned short* __restrict__ cmb1) {
    constexpr int NX8 = B_ * I_ / 8;   // 524288
    constexpr int NH8 = B_ * H_ / 8;   // 1048576
    int i = blockIdx.x * blockDim.x + threadIdx.x;
    if (i < NX8) {
        int row = i >> 6, c8 = i & 63;
        u16x8 o = cvt8((const float4*)x + (size_t)i * 2);
        *(u16x8*)(cmb1 + (size_t)row * K_ + c8 * 8) = o;
    } else if (i < NX8 + NH8) {
        int j = i - NX8;
        int row = j >> 7, c8 = j & 127;
        u16x8 o = cvt8((const float4*)hid + (size_t)j * 2);
        *(u16x8*)(cmb1 + (size_t)row * K_ + 512 + c8 * 8) = o;
    }
}

// ---- convert 3 weight matrices --------------------------------------------
__global__ void cvt_w3(const float* __restrict__ wt, const float* __restrict__ wr,
                       const float* __restrict__ wh,
                       unsigned short* __restrict__ wtb,
                       unsigned short* __restrict__ wrb,
                       unsigned short* __restrict__ whb) {
    constexpr int NW8 = H_ * K_ / 8;   // 196608
    int i = blockIdx.x * blockDim.x + threadIdx.x;
    const float* src; unsigned short* dst; int k;
    if (i < NW8)           { src = wt; dst = wtb; k = i; }
    else if (i < 2 * NW8)  { src = wr; dst = wrb; k = i - NW8; }
    else if (i < 3 * NW8)  { src = wh; dst = whb; k = i - 2 * NW8; }
    else return;
    u16x8 o = cvt8((const float4*)src + (size_t)k * 2);
    *(u16x8*)(dst + (size_t)k * 8) = o;
}

// ===========================================================================
// gemm4<MODE>: BM=256, BN=128, waves 4x2, BK=64, 2 tiles/iter, FOUR phases
// of 16 MFMA each (A-half x B-full; all 8 B-frags held in regs per tile).
// One barrier per phase. Stage-after-last-read (1-barrier separation):
//   P1: readA(lo,b0)+readB_all(b0); stage A-hi(odd tile 2j+1 -> b1)
//   P2: readA(hi,b0); stage A-lo+B(2j+2 -> b0); vmcnt(4)
//   P3: readA(lo,b1)+readB_all(b1); stage A-hi(2j+2 -> b0)
//   P4: readA(hi,b1); stage A-lo+B(2j+3 -> b1); vmcnt(4)
// vmcnt(4) at P2 drains {prev-P4's 4, P1's 2} -> b1 ready for P3/P4;
// vmcnt(4) at P4 drains {P2's 4, P3's 2} -> b0 ready for next P1/P2.
// MODE 0 (grid.z=2): z=0: itau_out=bf16(1/(softplus+eps));
//                    z=1: gate_out[m*K_+512+n]=bf16(sigmoid*hidden)
// MODE 1: A split (k<512 from A1=cmb1, k>=512 from A2=cmb2);
//         outF = hidden + (tanh(z)-hidden)*itau
// ===========================================================================
template<int MODE>
__global__ __launch_bounds__(512, 1)
void gemm4(const unsigned short* __restrict__ A1,
           const unsigned short* __restrict__ A2,
           const unsigned short* __restrict__ W0,
           const unsigned short* __restrict__ W1,
           const float* __restrict__ bias0,
           const float* __restrict__ bias1,
           const float* __restrict__ hidden,
           const unsigned short* __restrict__ itau_in,
           float* __restrict__ outF,
           unsigned short* __restrict__ itau_out,
           unsigned short* __restrict__ gate_out)
{
    extern __shared__ __align__(16) char lds[];
    // A: [0,65536) 2 bufs x 32768 ; B: [65536,98304) 2 bufs x 16384

    const int t = threadIdx.x;
    const int w = t >> 6, l = t & 63;
    const int bz = (MODE == 0) ? blockIdx.z : 0;
    const unsigned short* Wsel = (MODE == 0 && bz) ? W1 : W0;
    const float* bias = (MODE == 0 && bz) ? bias1 : bias0;

    const int wg  = blockIdx.y * 8 + blockIdx.x;
    const int swz = (wg & 7) * 32 + (wg >> 3);   // XCD c <- 4 m-panels x 8 n
    const int m0  = (swz >> 3) * 256;
    const int n0  = (swz & 7) * 128;

    const int srow  = t >> 3;
    const int sslot = ((t & 7) ^ (srow & 7)) * 8;
    const unsigned short* srcA1 = A1 + (size_t)(m0 + srow) * K_ + sslot;
    const unsigned short* srcA2 = A2 + (size_t)(m0 + srow) * K_ + sslot;
    const unsigned short* srcB  = Wsel + (size_t)(n0 + srow) * K_ + sslot;
    char* dstA = lds + w * 1024;
    char* dstB = lds + 65536 + w * 1024;

    auto stageA = [&](int tt, int h) {   // A half h = rows [h*128, h*128+128)
        const unsigned short* base = (MODE == 1 && tt >= 8) ? srcA2 : srcA1;
        const unsigned short* s = base + (size_t)(h * 128) * K_ + tt * 64;
        char* d = dstA + (tt & 1) * 32768 + h * 16384;
        #pragma unroll
        for (int j = 0; j < 2; ++j)
            __builtin_amdgcn_global_load_lds(
                (const AS1 void*)(s + (size_t)j * 64 * K_),
                (AS3 void*)(d + j * 8192), 16, 0, 0);
    };
    auto stageB = [&](int tt, int h) {   // B half h = rows [h*64, h*64+64)
        const unsigned short* s = srcB + (size_t)(h * 64) * K_ + tt * 64;
        char* d = dstB + (tt & 1) * 16384 + h * 8192;
        __builtin_amdgcn_global_load_lds((const AS1 void*)s, (AS3 void*)d, 16, 0, 0);
    };

    const int fr = l & 15, kq = l >> 4;
    const int wm = w >> 1, wn = w & 1;                 // waves 4 x 2
    const int fx = (kq ^ (fr & 7)) << 4;
    const char* rdA0 = lds + (wm * 32 + fr) * 128 + fx;
    const char* rdA1 = lds + (wm * 32 + fr) * 128 + (fx ^ 64);
    const char* rdB0 = lds + 65536 + (wn * 32 + fr) * 128 + fx;
    const char* rdB1 = lds + 65536 + (wn * 32 + fr) * 128 + (fx ^ 64);

    bf16x8 af[2][2], bfr[2][2][2];
    f32x4 acc[4][4];
    #pragma unroll
    for (int i = 0; i < 4; ++i)
        #pragma unroll
        for (int jn = 0; jn < 4; ++jn) acc[i][jn] = (f32x4)0.0f;

    auto readA = [&](int half, int par) {
        #pragma unroll
        for (int mi = 0; mi < 2; ++mi) {
            af[mi][0] = *(const bf16x8*)(rdA0 + par * 32768 + half * 16384 + mi * 2048);
            af[mi][1] = *(const bf16x8*)(rdA1 + par * 32768 + half * 16384 + mi * 2048);
        }
    };
    auto readBall = [&](int par) {       // all 4 n-frags x 2 k-slots of the tile
        #pragma unroll
        for (int bh = 0; bh < 2; ++bh)
            #pragma unroll
            for (int ni = 0; ni < 2; ++ni) {
                bfr[bh][ni][0] = *(const bf16x8*)(rdB0 + par * 16384 + bh * 8192 + ni * 2048);
                bfr[bh][ni][1] = *(const bf16x8*)(rdB1 + par * 16384 + bh * 8192 + ni * 2048);
            }
    };
    auto quad16 = [&](int ah) {          // 16 MFMA: both B-halves
        __builtin_amdgcn_s_setprio(1);
        #pragma unroll
        for (int bh = 0; bh < 2; ++bh)
            #pragma unroll
            for (int mi = 0; mi < 2; ++mi)
                #pragma unroll
                for (int ni = 0; ni < 2; ++ni)
                    #pragma unroll
                    for (int ks = 0; ks < 2; ++ks)
                        acc[ah * 2 + mi][bh * 2 + ni] =
                            __builtin_amdgcn_mfma_f32_16x16x32_bf16(
                                af[mi][ks], bfr[bh][ni][ks],
                                acc[ah * 2 + mi][bh * 2 + ni], 0, 0, 0);
        __builtin_amdgcn_s_setprio(0);
    };

    // prologue: t0 full (Alo,Ahi,B = 6) + t1 partial (Alo,B = 4); drain t0
    stageA(0, 0); stageA(0, 1); stageB(0, 0); stageB(0, 1);
    stageA(1, 0); stageB(1, 0); stageB(1, 1);
    vwait4(); barrier_();

    for (int j = 0; j < NITER; ++j) {
        const int tE = (2 * j + 2 < NT) ? 2 * j + 2 : 0;   // clamped redundant
        const int tO = (2 * j + 3 < NT) ? 2 * j + 3 : 0;
        // P1: buf0 A-lo x B-full; stage A-hi of odd tile (read at P4)
        readA(0, 0); readBall(0); stageA(2 * j + 1, 1);
        quad16(0); barrier_();
        // P2: buf0 A-hi; stage even-tile A-lo + B
        readA(1, 0); stageA(tE, 0); stageB(tE, 0); stageB(tE, 1);
        quad16(1); vwait4(); barrier_();
        // P3: buf1 A-lo x B-full; stage even-tile A-hi
        readA(0, 1); readBall(1); stageA(tE, 1);
        quad16(0); barrier_();
        // P4: buf1 A-hi; stage odd-tile A-lo + B
        readA(1, 1); stageA(tO, 0); stageB(tO, 0); stageB(tO, 1);
        quad16(1); vwait4(); barrier_();
    }
    asm volatile("s_waitcnt vmcnt(0)" ::: "memory");

    // epilogue: C/D layout col = lane&15, row = (lane>>4)*4 + jj
    const int rs4 = kq * 4;
    const int nB0 = n0 + wn * 32;
    const int mB0 = m0 + wm * 32;
    #pragma unroll
    for (int ah = 0; ah < 2; ++ah)
        #pragma unroll
        for (int mi = 0; mi < 2; ++mi)
            #pragma unroll
            for (int bh = 0; bh < 2; ++bh)
                #pragma unroll
                for (int ni = 0; ni < 2; ++ni) {
                    const int n = nB0 + bh * 64 + ni * 16 + fr;
                    const float bv = bias[n];
                    #pragma unroll
                    for (int jj = 0; jj < 4; ++jj) {
                        const int m = mB0 + ah * 128 + mi * 16 + rs4 + jj;
                        const size_t ix = (size_t)m * H_ + n;
                        const float z = acc[ah * 2 + mi][bh * 2 + ni][jj] + bv;
                        if (MODE == 0) {
                            if (bz == 0) {
                                const float sp = (z > 15.f) ? z
                                               : __logf(1.0f + __expf(z));
                                itau_out[ix] = f2bf(__fdividef(1.0f, sp + 1e-6f));
                            } else {
                                const float r = __fdividef(1.0f, 1.0f + __expf(-z));
                                gate_out[(size_t)m * K_ + 512 + n] = f2bf(r * hidden[ix]);
                            }
                        } else {
                            const float e2 = __expf(2.0f * z);
                            const float th = __fdividef(e2 - 1.0f, e2 + 1.0f);
                            const float h = hidden[ix];
                            const float it = __uint_as_float(((unsigned)itau_in[ix]) << 16);
                            outF[ix] = h + (th - h) * it;
                        }
                    }
                }
}

extern "C" void kernel_launch(void* const* d_in, const int* in_sizes, int n_in,
                              void* d_out, int out_size, void* d_ws, size_t ws_size,
                              hipStream_t stream) {
    (void)in_sizes; (void)n_in; (void)out_size; (void)ws_size;

    const float* x     = (const float*)d_in[0];
    const float* hid   = (const float*)d_in[1];
    const float* W_tau = (const float*)d_in[2];
    const float* b_tau = (const float*)d_in[3];
    const float* W_r   = (const float*)d_in[4];
    const float* b_r   = (const float*)d_in[5];
    const float* W_h   = (const float*)d_in[6];
    const float* b_h   = (const float*)d_in[7];

    // workspace (~76.5 MB)
    unsigned short* cmb1 = (unsigned short*)d_ws;          // [8192][1536] = [x|hidden]
    unsigned short* cmb2 = cmb1 + (size_t)B_ * K_;         // [8192][1536] (gated in cols 512+)
    unsigned short* wtb  = cmb2 + (size_t)B_ * K_;         // [1024][1536]
    unsigned short* wrb  = wtb  + (size_t)H_ * K_;         // [1024][1536]
    unsigned short* whb  = wrb  + (size_t)H_ * K_;         // [1024][1536]
    unsigned short* itau = whb  + (size_t)H_ * K_;         // [8192][1024] bf16

    hipFuncSetAttribute(reinterpret_cast<const void*>(&gemm4<0>),
                        hipFuncAttributeMaxDynamicSharedMemorySize, 98304);
    hipFuncSetAttribute(reinterpret_cast<const void*>(&gemm4<1>),
                        hipFuncAttributeMaxDynamicSharedMemorySize, 98304);

    const int th = 256;
    constexpr int NPACK = B_ * I_ / 8 + B_ * H_ / 8;   // 1572864
    pack_xh<<<NPACK / th, th, 0, stream>>>(x, hid, cmb1);
    constexpr int NW3 = 3 * H_ * K_ / 8;               // 589824
    cvt_w3<<<NW3 / th, th, 0, stream>>>(W_tau, W_r, W_h, wtb, wrb, whb);

    dim3 g0(8, 32, 2);   // z=0: tau, z=1: r
    gemm4<0><<<g0, 512, 98304, stream>>>(cmb1, cmb1, wtb, wrb, b_tau, b_r,
                                         hid, nullptr, nullptr, itau, cmb2);
    dim3 g1(8, 32, 1);
    gemm4<1><<<g1, 512, 98304, stream>>>(cmb1, cmb2, whb, nullptr, b_h, nullptr,
                                         hid, itau, (float*)d_out, nullptr, nullptr);
}

// Round 9
// 105.944 us; speedup vs baseline: 2.1611x; 1.1802x over previous
//
#include <hip/hip_runtime.h>
#include <hip/hip_bf16.h>

typedef __attribute__((ext_vector_type(8))) unsigned short u16x8;
typedef __attribute__((ext_vector_type(8))) __bf16        bf16x8;
typedef __attribute__((ext_vector_type(4))) float         f32x4;

static constexpr int B_ = 8192;
static constexpr int I_ = 512;
static constexpr int H_ = 1024;
static constexpr int K_ = 1536;   // I_ + H_
static constexpr int NT    = K_ / 64;   // 24 K-tiles of BK=64
static constexpr int NITER = NT / 2;    // 12 iterations (2 tiles each)

#define AS1 __attribute__((address_space(1)))
#define AS3 __attribute__((address_space(3)))

__device__ __forceinline__ unsigned short f2bf(float f) {
    unsigned int u = __float_as_uint(f);
    u += 0x7FFF + ((u >> 16) & 1);          // RNE
    return (unsigned short)(u >> 16);
}

__device__ __forceinline__ void memfence() { asm volatile("" ::: "memory"); }
__device__ __forceinline__ void barrier_() {
    memfence(); __builtin_amdgcn_s_barrier(); memfence();
}
__device__ __forceinline__ void vwait6() {
    asm volatile("s_waitcnt vmcnt(6)" ::: "memory");
    __builtin_amdgcn_sched_barrier(0);
}
__device__ __forceinline__ void vwait4() {
    asm volatile("s_waitcnt vmcnt(4)" ::: "memory");
    __builtin_amdgcn_sched_barrier(0);
}

__device__ __forceinline__ u16x8 cvt8(const float4* s) {
    float4 a = s[0], b = s[1];
    u16x8 o;
    o[0] = f2bf(a.x); o[1] = f2bf(a.y); o[2] = f2bf(a.z); o[3] = f2bf(a.w);
    o[4] = f2bf(b.x); o[5] = f2bf(b.y); o[6] = f2bf(b.z); o[7] = f2bf(b.w);
    return o;
}

// ---- one-launch input prep: [x|hid]->cmb1 bf16, 3x W -> bf16 ---------------
__global__ void prep(const float* __restrict__ x, const float* __restrict__ hid,
                     const float* __restrict__ wt, const float* __restrict__ wr,
                     const float* __restrict__ wh,
                     unsigned short* __restrict__ cmb1,
                     unsigned short* __restrict__ wtb,
                     unsigned short* __restrict__ wrb,
                     unsigned short* __restrict__ whb) {
    constexpr int NX8 = B_ * I_ / 8;    // 524288
    constexpr int NH8 = B_ * H_ / 8;    // 1048576
    constexpr int NW8 = H_ * K_ / 8;    // 196608
    int i = blockIdx.x * blockDim.x + threadIdx.x;
    if (i < NX8) {
        int row = i >> 6, c8 = i & 63;
        u16x8 o = cvt8((const float4*)x + (size_t)i * 2);
        *(u16x8*)(cmb1 + (size_t)row * K_ + c8 * 8) = o;
    } else if (i < NX8 + NH8) {
        int j = i - NX8;
        int row = j >> 7, c8 = j & 127;
        u16x8 o = cvt8((const float4*)hid + (size_t)j * 2);
        *(u16x8*)(cmb1 + (size_t)row * K_ + 512 + c8 * 8) = o;
    } else {
        int k = i - (NX8 + NH8);
        const float* src; unsigned short* dst;
        if (k < NW8)          { src = wt; dst = wtb; }
        else if (k < 2 * NW8) { src = wr; dst = wrb; k -= NW8; }
        else                  { src = wh; dst = whb; k -= 2 * NW8; }
        u16x8 o = cvt8((const float4*)src + (size_t)k * 2);
        *(u16x8*)(dst + (size_t)k * 8) = o;
    }
}

// ===========================================================================
// gemm_tr: FUSED tau+r. BM=256, BN=128, waves 4x2, BK=64, 2 tiles/iter.
// Per tile TWO phases of 32 MFMA: {readA_full+readB(W0); MFMA W0} then
// {readB(W1); MFMA W1} (A-frags held in regs across both).
// LDS: A 2x32K at 0; B 2x{W0 16K|W1 16K} at 65536. 128 KiB total.
// Stage-after-last-read (>=1 barrier), re-derived:
//   P1: rd A(b0)+BW0(b0); stage BW1(2j+1->b1)          [A,BW0 b0 last rd here? A&BW0 read here; BW1(b1) last read prev-P4 -> ok]
//   P2: rd BW1(b0);       stage A(tE->b0)+BW0(tE->b0); vmcnt(6)
//   P3: rd A(b1)+BW0(b1); stage BW1(tE->b0)
//   P4: rd BW1(b1);       stage A(tO->b1)+BW0(tO->b1); vmcnt(6)
// vmcnt(6)@P2 drains prevP4(6)+P1(2) -> b1 ready; @P4 drains P2(6)+P3(2) -> b0.
//   epilogue: itau_out = bf16(1/(softplus(z)+eps)); gate = bf16(sig*hid)
// ===========================================================================
__global__ __launch_bounds__(512, 1)
void gemm_tr(const unsigned short* __restrict__ A,
             const unsigned short* __restrict__ W0,
             const unsigned short* __restrict__ W1,
             const float* __restrict__ b0,
             const float* __restrict__ b1,
             const float* __restrict__ hidden,
             unsigned short* __restrict__ itau_out,
             unsigned short* __restrict__ gate_out)
{
    extern __shared__ __align__(16) char lds[];

    const int t = threadIdx.x;
    const int w = t >> 6, l = t & 63;
    const int wg  = blockIdx.y * 8 + blockIdx.x;
    const int swz = (wg & 7) * 32 + (wg >> 3);   // XCD c <- 4 m-panels x 8 n
    const int m0  = (swz >> 3) * 256;
    const int n0  = (swz & 7) * 128;

    const int srow  = t >> 3;
    const int sslot = ((t & 7) ^ (srow & 7)) * 8;
    const unsigned short* srcA  = A  + (size_t)(m0 + srow) * K_ + sslot;
    const unsigned short* srcB0 = W0 + (size_t)(n0 + srow) * K_ + sslot;
    const unsigned short* srcB1 = W1 + (size_t)(n0 + srow) * K_ + sslot;
    char* dstA = lds + w * 1024;
    char* dstB = lds + 65536 + w * 1024;

    auto stageA = [&](int tt) {          // full A tile: 4 loads
        const unsigned short* s = srcA + tt * 64;
        char* d = dstA + (tt & 1) * 32768;
        #pragma unroll
        for (int q = 0; q < 4; ++q)
            __builtin_amdgcn_global_load_lds(
                (const AS1 void*)(s + (size_t)q * 64 * K_),
                (AS3 void*)(d + q * 8192), 16, 0, 0);
    };
    auto stageB = [&](int tt, int wi) {  // one W tile: 2 loads
        const unsigned short* s = (wi ? srcB1 : srcB0) + tt * 64;
        char* d = dstB + (tt & 1) * 32768 + wi * 16384;
        #pragma unroll
        for (int h = 0; h < 2; ++h)
            __builtin_amdgcn_global_load_lds(
                (const AS1 void*)(s + (size_t)(h * 64) * K_),
                (AS3 void*)(d + h * 8192), 16, 0, 0);
    };

    const int fr = l & 15, kq = l >> 4;
    const int wm = w >> 1, wn = w & 1;                 // waves 4 x 2
    const int fx = (kq ^ (fr & 7)) << 4;
    const char* rdA0 = lds + (wm * 32 + fr) * 128 + fx;
    const char* rdA1 = lds + (wm * 32 + fr) * 128 + (fx ^ 64);
    const char* rdB0 = lds + 65536 + (wn * 32 + fr) * 128 + fx;
    const char* rdB1 = lds + 65536 + (wn * 32 + fr) * 128 + (fx ^ 64);

    bf16x8 af[4][2], bfr[2][2][2];       // af: full A tile; bfr: one W
    f32x4 acc[2][4][4];
    #pragma unroll
    for (int wi = 0; wi < 2; ++wi)
        #pragma unroll
        for (int i = 0; i < 4; ++i)
            #pragma unroll
            for (int jn = 0; jn < 4; ++jn) acc[wi][i][jn] = (f32x4)0.0f;

    auto readAfull = [&](int par) {      // 8 x b128: mf = ah*2+mi
        #pragma unroll
        for (int mf = 0; mf < 4; ++mf) {
            const int off = par * 32768 + (mf >> 1) * 16384 + (mf & 1) * 2048;
            af[mf][0] = *(const bf16x8*)(rdA0 + off);
            af[mf][1] = *(const bf16x8*)(rdA1 + off);
        }
    };
    auto readB = [&](int wi, int par) {  // 8 x b128: one W, full tile
        #pragma unroll
        for (int bh = 0; bh < 2; ++bh)
            #pragma unroll
            for (int ni = 0; ni < 2; ++ni) {
                const int off = par * 32768 + wi * 16384 + bh * 8192 + ni * 2048;
                bfr[bh][ni][0] = *(const bf16x8*)(rdB0 + off);
                bfr[bh][ni][1] = *(const bf16x8*)(rdB1 + off);
            }
    };
    auto mfma32 = [&](int wi) {          // 32 MFMA: all m-frags x held W
        __builtin_amdgcn_s_setprio(1);
        #pragma unroll
        for (int mf = 0; mf < 4; ++mf)
            #pragma unroll
            for (int bh = 0; bh < 2; ++bh)
                #pragma unroll
                for (int ni = 0; ni < 2; ++ni)
                    #pragma unroll
                    for (int ks = 0; ks < 2; ++ks)
                        acc[wi][mf][bh * 2 + ni] =
                            __builtin_amdgcn_mfma_f32_16x16x32_bf16(
                                af[mf][ks], bfr[bh][ni][ks],
                                acc[wi][mf][bh * 2 + ni], 0, 0, 0);
        __builtin_amdgcn_s_setprio(0);
    };

    // prologue: t0 full (A4+BW0 2+BW1 2 = 8) + t1 partial (A4+BW0 2 = 6)
    stageA(0); stageB(0, 0); stageB(0, 1);
    stageA(1); stageB(1, 0);
    vwait6(); barrier_();

    for (int j = 0; j < NITER; ++j) {
        const int tE = (2 * j + 2 < NT) ? 2 * j + 2 : 0;   // clamped redundant
        const int tO = (2 * j + 3 < NT) ? 2 * j + 3 : 0;
        // P1: A(b0)+BW0(b0); stage BW1 of odd tile (BW1(b1) last read prev-P4)
        readAfull(0); readB(0, 0); stageB(2 * j + 1, 1);
        mfma32(0); barrier_();
        // P2: BW1(b0); stage even-tile A + BW0 (A,BW0 of b0 last read P1)
        readB(1, 0); stageA(tE); stageB(tE, 0);
        mfma32(1); vwait6(); barrier_();
        // P3: A(b1)+BW0(b1); stage even-tile BW1 (BW1(b0) last read P2)
        readAfull(1); readB(0, 1); stageB(tE, 1);
        mfma32(0); barrier_();
        // P4: BW1(b1); stage odd-tile A + BW0 (A,BW0 of b1 last read P3)
        readB(1, 1); stageA(tO); stageB(tO, 0);
        mfma32(1); vwait6(); barrier_();
    }
    asm volatile("s_waitcnt vmcnt(0)" ::: "memory");

    // epilogue: C/D col = lane&15, row = (lane>>4)*4 + jj
    const int rs4 = kq * 4;
    const int nB0 = n0 + wn * 32;
    #pragma unroll
    for (int wi = 0; wi < 2; ++wi)
        #pragma unroll
        for (int mf = 0; mf < 4; ++mf)
            #pragma unroll
            for (int bh = 0; bh < 2; ++bh)
                #pragma unroll
                for (int ni = 0; ni < 2; ++ni) {
                    const int n = nB0 + bh * 64 + ni * 16 + fr;
                    const float bv = (wi ? b1 : b0)[n];
                    #pragma unroll
                    for (int jj = 0; jj < 4; ++jj) {
                        const int m = m0 + (mf >> 1) * 128 + wm * 32 + (mf & 1) * 16 + rs4 + jj;
                        const size_t ix = (size_t)m * H_ + n;
                        const float z = acc[wi][mf][bh * 2 + ni][jj] + bv;
                        if (wi == 0) {
                            const float sp = (z > 15.f) ? z : __logf(1.0f + __expf(z));
                            itau_out[ix] = f2bf(__fdividef(1.0f, sp + 1e-6f));
                        } else {
                            const float r = __fdividef(1.0f, 1.0f + __expf(-z));
                            gate_out[(size_t)m * K_ + 512 + n] = f2bf(r * hidden[ix]);
                        }
                    }
                }
}

// ===========================================================================
// gemm_h: R8-proven 4-phase kernel (BM=256, BN=128, waves 4x2, 16-MFMA
// phases, vmcnt(4)). A split: k<512 from cmb1, k>=512 from cmb2 (gated).
//   outF = hidden + (tanh(z)-hidden)*itau
// ===========================================================================
__global__ __launch_bounds__(512, 1)
void gemm_h(const unsigned short* __restrict__ A1,
            const unsigned short* __restrict__ A2,
            const unsigned short* __restrict__ W0,
            const float* __restrict__ bias0,
            const float* __restrict__ hidden,
            const unsigned short* __restrict__ itau_in,
            float* __restrict__ outF)
{
    extern __shared__ __align__(16) char lds[];

    const int t = threadIdx.x;
    const int w = t >> 6, l = t & 63;
    const int wg  = blockIdx.y * 8 + blockIdx.x;
    const int swz = (wg & 7) * 32 + (wg >> 3);
    const int m0  = (swz >> 3) * 256;
    const int n0  = (swz & 7) * 128;

    const int srow  = t >> 3;
    const int sslot = ((t & 7) ^ (srow & 7)) * 8;
    const unsigned short* srcA1 = A1 + (size_t)(m0 + srow) * K_ + sslot;
    const unsigned short* srcA2 = A2 + (size_t)(m0 + srow) * K_ + sslot;
    const unsigned short* srcB  = W0 + (size_t)(n0 + srow) * K_ + sslot;
    char* dstA = lds + w * 1024;
    char* dstB = lds + 65536 + w * 1024;

    auto stageA = [&](int tt, int h) {
        const unsigned short* base = (tt >= 8) ? srcA2 : srcA1;
        const unsigned short* s = base + (size_t)(h * 128) * K_ + tt * 64;
        char* d = dstA + (tt & 1) * 32768 + h * 16384;
        #pragma unroll
        for (int j = 0; j < 2; ++j)
            __builtin_amdgcn_global_load_lds(
                (const AS1 void*)(s + (size_t)j * 64 * K_),
                (AS3 void*)(d + j * 8192), 16, 0, 0);
    };
    auto stageB = [&](int tt, int h) {
        const unsigned short* s = srcB + (size_t)(h * 64) * K_ + tt * 64;
        char* d = dstB + (tt & 1) * 16384 + h * 8192;
        __builtin_amdgcn_global_load_lds((const AS1 void*)s, (AS3 void*)d, 16, 0, 0);
    };

    const int fr = l & 15, kq = l >> 4;
    const int wm = w >> 1, wn = w & 1;
    const int fx = (kq ^ (fr & 7)) << 4;
    const char* rdA0 = lds + (wm * 32 + fr) * 128 + fx;
    const char* rdA1 = lds + (wm * 32 + fr) * 128 + (fx ^ 64);
    const char* rdB0 = lds + 65536 + (wn * 32 + fr) * 128 + fx;
    const char* rdB1 = lds + 65536 + (wn * 32 + fr) * 128 + (fx ^ 64);

    bf16x8 af[2][2], bfr[2][2][2];
    f32x4 acc[4][4];
    #pragma unroll
    for (int i = 0; i < 4; ++i)
        #pragma unroll
        for (int jn = 0; jn < 4; ++jn) acc[i][jn] = (f32x4)0.0f;

    auto readA = [&](int half, int par) {
        #pragma unroll
        for (int mi = 0; mi < 2; ++mi) {
            af[mi][0] = *(const bf16x8*)(rdA0 + par * 32768 + half * 16384 + mi * 2048);
            af[mi][1] = *(const bf16x8*)(rdA1 + par * 32768 + half * 16384 + mi * 2048);
        }
    };
    auto readBall = [&](int par) {
        #pragma unroll
        for (int bh = 0; bh < 2; ++bh)
            #pragma unroll
            for (int ni = 0; ni < 2; ++ni) {
                bfr[bh][ni][0] = *(const bf16x8*)(rdB0 + par * 16384 + bh * 8192 + ni * 2048);
                bfr[bh][ni][1] = *(const bf16x8*)(rdB1 + par * 16384 + bh * 8192 + ni * 2048);
            }
    };
    auto quad16 = [&](int ah) {
        __builtin_amdgcn_s_setprio(1);
        #pragma unroll
        for (int bh = 0; bh < 2; ++bh)
            #pragma unroll
            for (int mi = 0; mi < 2; ++mi)
                #pragma unroll
                for (int ni = 0; ni < 2; ++ni)
                    #pragma unroll
                    for (int ks = 0; ks < 2; ++ks)
                        acc[ah * 2 + mi][bh * 2 + ni] =
                            __builtin_amdgcn_mfma_f32_16x16x32_bf16(
                                af[mi][ks], bfr[bh][ni][ks],
                                acc[ah * 2 + mi][bh * 2 + ni], 0, 0, 0);
        __builtin_amdgcn_s_setprio(0);
    };

    stageA(0, 0); stageA(0, 1); stageB(0, 0); stageB(0, 1);
    stageA(1, 0); stageB(1, 0); stageB(1, 1);
    vwait4(); barrier_();

    for (int j = 0; j < NITER; ++j) {
        const int tE = (2 * j + 2 < NT) ? 2 * j + 2 : 0;
        const int tO = (2 * j + 3 < NT) ? 2 * j + 3 : 0;
        readA(0, 0); readBall(0); stageA(2 * j + 1, 1);
        quad16(0); barrier_();
        readA(1, 0); stageA(tE, 0); stageB(tE, 0); stageB(tE, 1);
        quad16(1); vwait4(); barrier_();
        readA(0, 1); readBall(1); stageA(tE, 1);
        quad16(0); barrier_();
        readA(1, 1); stageA(tO, 0); stageB(tO, 0); stageB(tO, 1);
        quad16(1); vwait4(); barrier_();
    }
    asm volatile("s_waitcnt vmcnt(0)" ::: "memory");

    const int rs4 = kq * 4;
    const int nB0 = n0 + wn * 32;
    const int mB0 = m0 + wm * 32;
    #pragma unroll
    for (int ah = 0; ah < 2; ++ah)
        #pragma unroll
        for (int mi = 0; mi < 2; ++mi)
            #pragma unroll
            for (int bh = 0; bh < 2; ++bh)
                #pragma unroll
                for (int ni = 0; ni < 2; ++ni) {
                    const int n = nB0 + bh * 64 + ni * 16 + fr;
                    const float bv = bias0[n];
                    #pragma unroll
                    for (int jj = 0; jj < 4; ++jj) {
                        const int m = mB0 + ah * 128 + mi * 16 + rs4 + jj;
                        const size_t ix = (size_t)m * H_ + n;
                        const float z = acc[ah * 2 + mi][bh * 2 + ni][jj] + bv;
                        const float e2 = __expf(2.0f * z);
                        const float th = __fdividef(e2 - 1.0f, e2 + 1.0f);
                        const float h = hidden[ix];
                        const float it = __uint_as_float(((unsigned)itau_in[ix]) << 16);
                        outF[ix] = h + (th - h) * it;
                    }
                }
}

extern "C" void kernel_launch(void* const* d_in, const int* in_sizes, int n_in,
                              void* d_out, int out_size, void* d_ws, size_t ws_size,
                              hipStream_t stream) {
    (void)in_sizes; (void)n_in; (void)out_size; (void)ws_size;

    const float* x     = (const float*)d_in[0];
    const float* hid   = (const float*)d_in[1];
    const float* W_tau = (const float*)d_in[2];
    const float* b_tau = (const float*)d_in[3];
    const float* W_r   = (const float*)d_in[4];
    const float* b_r   = (const float*)d_in[5];
    const float* W_h   = (const float*)d_in[6];
    const float* b_h   = (const float*)d_in[7];

    // workspace (~76.5 MB)
    unsigned short* cmb1 = (unsigned short*)d_ws;          // [8192][1536] = [x|hidden]
    unsigned short* cmb2 = cmb1 + (size_t)B_ * K_;         // [8192][1536] (gated in cols 512+)
    unsigned short* wtb  = cmb2 + (size_t)B_ * K_;         // [1024][1536]
    unsigned short* wrb  = wtb  + (size_t)H_ * K_;         // [1024][1536]
    unsigned short* whb  = wrb  + (size_t)H_ * K_;         // [1024][1536]
    unsigned short* itau = whb  + (size_t)H_ * K_;         // [8192][1024] bf16

    hipFuncSetAttribute(reinterpret_cast<const void*>(&gemm_tr),
                        hipFuncAttributeMaxDynamicSharedMemorySize, 131072);
    hipFuncSetAttribute(reinterpret_cast<const void*>(&gemm_h),
                        hipFuncAttributeMaxDynamicSharedMemorySize, 98304);

    const int th = 256;
    constexpr int NPREP = B_ * I_ / 8 + B_ * H_ / 8 + 3 * H_ * K_ / 8; // 2162688
    prep<<<NPREP / th, th, 0, stream>>>(x, hid, W_tau, W_r, W_h,
                                        cmb1, wtb, wrb, whb);

    dim3 g(8, 32);   // 256 blocks, 1/CU
    gemm_tr<<<g, 512, 131072, stream>>>(cmb1, wtb, wrb, b_tau, b_r, hid,
                                        itau, cmb2);
    gemm_h<<<g, 512, 98304, stream>>>(cmb1, cmb2, whb, b_h, hid, itau,
                                      (float*)d_out);
}